// Round 7
// baseline (211.331 us; speedup 1.0000x reference)
//
#include <hip/hip_runtime.h>

// ZNCC fused kernel. [16,3,512,512] f32 -> [16,1,512,512] f32.
// 5x5 box means (zero pad, /25); second 5x5 box over centered products.
//
// R7 = R6 ring + (a) HS=8 -> LDS 39.9KB -> 4 blocks/CU (12 waves), grid 2048
// (8 blocks/CU -> two clean residency rounds, no 3+1 tail); (b) prefetch
// depth 2 (ping-pong reg sets; global loads issued 2 iters before their
// ds_write); (c) old-row + center-row ds_reads hoisted to iter top, before
// the write; (d) rolling vertical hp sums (retire/add, not 5-term recompute).
// Ring is wave-private (no barriers in main loop); cross-lane LDS reuse
// requires the zero-cost asm fences (compiler ordering only).

constexpr int W = 512, H = 512, Cn = 3, Bn = 16;
constexpr int HS = 8;         // output rows per segment
constexpr int STRIPW = 256;   // output cols per wave strip
constexpr int RW = 264;       // ring row width (cols s0-4 .. s0+259)
constexpr int RING_CH = 5 * 2 * RW;                  // 2640 floats per channel
constexpr int ACC_OFF = Cn * RING_CH;                // 7920
constexpr int SMEM_FLOATS = ACC_OFF + HS * STRIPW;   // 9968 floats = 39872 B

#define LDS_FENCE() asm volatile("" ::: "memory")

__global__ __launch_bounds__(192) void zncc_ring(const float* __restrict__ xg,
                                                 const float* __restrict__ yg,
                                                 float* __restrict__ outg) {
    __shared__ float smem[SMEM_FLOATS];

    const int tid   = threadIdx.x;
    const int lane  = tid & 63;
    const int ch    = tid >> 6;
    const int bx    = blockIdx.x;   // seg*2 + strip
    const int seg   = bx >> 1;
    const int strip = bx & 1;
    const int b     = blockIdx.y;
    const int o0    = seg * HS;
    const int s0    = strip * STRIPW;

    float* acc = smem + ACC_OFF;
    for (int i = tid; i < HS * STRIPW / 4; i += 192)
        ((float4*)acc)[i] = make_float4(0.f, 0.f, 0.f, 0.f);
    __syncthreads();

    const float* __restrict__ xp = xg + (size_t)(b * Cn + ch) * (H * W);
    const float* __restrict__ yp = yg + (size_t)(b * Cn + ch) * (H * W);

    float* ring = smem + ch * RING_CH;
    const int rs = 4 * lane;                 // per-lane span start in ring row

    const int g0 = s0 - 4 + 4 * lane;
    const int g1 = s0 + 252 + 4 * lane;
    const bool ok0 = (g0 >= 0) && (g0 + 3 < W);   // false only strip0 lane0
    const bool ex  = (lane < 2);
    const bool ok1 = ex && (g1 + 3 < W);          // false for strip1 lane1

    // zero-product masks for out-of-image product cols (cols m0-2+i)
    const float pmA = (strip == 0 && lane == 0) ? 0.f : 1.f;   // i = 0,1
    const float pmB = (strip == 1 && lane == 63) ? 0.f : 1.f;  // i = 6,7

    float vsx[12], vsy[12];        // rolling vertical 5-row raw sums (span)
#pragma unroll
    for (int i = 0; i < 12; ++i) { vsx[i] = 0.f; vsy[i] = 0.f; }
    float hq[5][3][4];             // hp history [slot][xx,xy,yy][j]
#pragma unroll
    for (int s = 0; s < 5; ++s)
#pragma unroll
        for (int t = 0; t < 3; ++t)
#pragma unroll
            for (int j = 0; j < 4; ++j) hq[s][t][j] = 0.f;
    float oxx[4], oxy[4], oyy[4];  // rolling vertical hp 5-sums
#pragma unroll
    for (int j = 0; j < 4; ++j) { oxx[j] = 0.f; oxy[j] = 0.f; oyy[j] = 0.f; }

    // two prefetch register sets (depth-2 ping-pong)
    float4 pax0, pay0, pax1, pay1;  // set A (even k)
    float4 pbx0, pby0, pbx1, pby1;  // set B (odd k)

    auto loadA = [&](int L) {
        pax0 = pay0 = pax1 = pay1 = make_float4(0.f, 0.f, 0.f, 0.f);
        if (L >= 0 && L < H) {
            const float* xr = xp + ((size_t)L << 9);
            const float* yr = yp + ((size_t)L << 9);
            if (ok0) { pax0 = *(const float4*)(xr + g0); pay0 = *(const float4*)(yr + g0); }
            if (ok1) { pax1 = *(const float4*)(xr + g1); pay1 = *(const float4*)(yr + g1); }
        }
    };
    auto loadB = [&](int L) {
        pbx0 = pby0 = pbx1 = pby1 = make_float4(0.f, 0.f, 0.f, 0.f);
        if (L >= 0 && L < H) {
            const float* xr = xp + ((size_t)L << 9);
            const float* yr = yp + ((size_t)L << 9);
            if (ok0) { pbx0 = *(const float4*)(xr + g0); pby0 = *(const float4*)(yr + g0); }
            if (ok1) { pbx1 = *(const float4*)(xr + g1); pby1 = *(const float4*)(yr + g1); }
        }
    };
    auto writeA = [&](int off) {
        *(float4*)(ring + off + rs) = pax0;
        *(float4*)(ring + off + RW + rs) = pay0;
        if (ex) {
            *(float4*)(ring + off + 256 + 4 * lane) = pax1;
            *(float4*)(ring + off + RW + 256 + 4 * lane) = pay1;
        }
    };
    auto writeB = [&](int off) {
        *(float4*)(ring + off + rs) = pbx0;
        *(float4*)(ring + off + RW + rs) = pby0;
        if (ex) {
            *(float4*)(ring + off + 256 + 4 * lane) = pbx1;
            *(float4*)(ring + off + RW + 256 + 4 * lane) = pby1;
        }
    };
    auto readspan = [&](int off, float* dx, float* dy) {
        float4 a0 = *(const float4*)(ring + off + rs);
        float4 a1 = *(const float4*)(ring + off + rs + 4);
        float4 a2 = *(const float4*)(ring + off + rs + 8);
        float4 b0 = *(const float4*)(ring + off + RW + rs);
        float4 b1 = *(const float4*)(ring + off + RW + rs + 4);
        float4 b2 = *(const float4*)(ring + off + RW + rs + 8);
        dx[0]=a0.x; dx[1]=a0.y; dx[2]=a0.z; dx[3]=a0.w;
        dx[4]=a1.x; dx[5]=a1.y; dx[6]=a1.z; dx[7]=a1.w;
        dx[8]=a2.x; dx[9]=a2.y; dx[10]=a2.z; dx[11]=a2.w;
        dy[0]=b0.x; dy[1]=b0.y; dy[2]=b0.z; dy[3]=b0.w;
        dy[4]=b1.x; dy[5]=b1.y; dy[6]=b1.z; dy[7]=b1.w;
        dy[8]=b2.x; dy[9]=b2.y; dy[10]=b2.z; dy[11]=b2.w;
    };

    // iter k (0..15): stage row L = o0-4+k into slot k%5; vsum = rows L-4..L;
    // products/hp at center V = L-2 (k>=4, slot (k-2)%5); output O = o0+k-8.
    loadA(o0 - 4);   // k=0's row
    loadB(o0 - 3);   // k=1's row

#pragma unroll
    for (int k = 0; k < HS + 8; ++k) {
        const int slot = k % 5;                 // compile-time (unrolled)
        const int off  = 2 * RW * slot;
        const int L    = o0 - 4 + k;
        const int V    = L - 2;

        // ---- hoisted LDS reads (both from slots NOT written this iter) ----
        float osx[12], osy[12];
        if (k >= 5) readspan(off, osx, osy);    // old row L-5 (pre-overwrite)

        float csx[12], csy[12];
        bool centerValid = false;
        if (k >= 4) {
            centerValid = (V >= 0) && (V < H);  // uniform
            if (centerValid) readspan(2 * RW * ((k - 2) % 5), csx, csy);
        }

        if (k >= 5) {
#pragma unroll
            for (int i = 0; i < 12; ++i) { vsx[i] -= osx[i]; vsy[i] -= osy[i]; }
        }

        LDS_FENCE();                            // reads before same-slot write
        if (k & 1) writeB(off); else writeA(off);
        LDS_FENCE();                            // write before cross-lane read
        // refill the set just consumed: row for iter k+2
        if (k & 1) loadB(o0 - 2 + k); else loadA(o0 - 2 + k);

        float nsx[12], nsy[12];
        readspan(off, nsx, nsy);                // new row incl neighbor cols
#pragma unroll
        for (int i = 0; i < 12; ++i) { vsx[i] += nsx[i]; vsy[i] += nsy[i]; }

        if (k >= 4) {
            // retire hp row V-5 from rolling sums (slot about to be overwritten)
#pragma unroll
            for (int j = 0; j < 4; ++j) {
                oxx[j] -= hq[slot][0][j]; oxy[j] -= hq[slot][1][j]; oyy[j] -= hq[slot][2][j];
            }
            if (centerValid) {
                // sliding 25-sums -> centered values at product cols m0-2+i
                float xc[8], yc[8];
                float sxw = vsx[0] + vsx[1] + vsx[2] + vsx[3] + vsx[4];
                float syw = vsy[0] + vsy[1] + vsy[2] + vsy[3] + vsy[4];
#pragma unroll
                for (int i = 0; i < 8; ++i) {
                    if (i) { sxw += vsx[i + 4] - vsx[i - 1]; syw += vsy[i + 4] - vsy[i - 1]; }
                    xc[i] = csx[i + 2] - sxw * 0.04f;
                    yc[i] = csy[i + 2] - syw * 0.04f;
                }
                xc[0] *= pmA; yc[0] *= pmA; xc[1] *= pmA; yc[1] *= pmA;
                xc[6] *= pmB; yc[6] *= pmB; xc[7] *= pmB; yc[7] *= pmB;
                // products + rolling horizontal 5-sums -> hq[slot], += o-sums
                {
                    float p[8];
#pragma unroll
                    for (int i = 0; i < 8; ++i) p[i] = xc[i] * xc[i];
                    float h = p[0] + p[1] + p[2] + p[3] + p[4];
                    hq[slot][0][0] = h; oxx[0] += h;
                    h += p[5] - p[0]; hq[slot][0][1] = h; oxx[1] += h;
                    h += p[6] - p[1]; hq[slot][0][2] = h; oxx[2] += h;
                    h += p[7] - p[2]; hq[slot][0][3] = h; oxx[3] += h;
                }
                {
                    float p[8];
#pragma unroll
                    for (int i = 0; i < 8; ++i) p[i] = xc[i] * yc[i];
                    float h = p[0] + p[1] + p[2] + p[3] + p[4];
                    hq[slot][1][0] = h; oxy[0] += h;
                    h += p[5] - p[0]; hq[slot][1][1] = h; oxy[1] += h;
                    h += p[6] - p[1]; hq[slot][1][2] = h; oxy[2] += h;
                    h += p[7] - p[2]; hq[slot][1][3] = h; oxy[3] += h;
                }
                {
                    float p[8];
#pragma unroll
                    for (int i = 0; i < 8; ++i) p[i] = yc[i] * yc[i];
                    float h = p[0] + p[1] + p[2] + p[3] + p[4];
                    hq[slot][2][0] = h; oyy[0] += h;
                    h += p[5] - p[0]; hq[slot][2][1] = h; oyy[1] += h;
                    h += p[6] - p[1]; hq[slot][2][2] = h; oyy[2] += h;
                    h += p[7] - p[2]; hq[slot][2][3] = h; oyy[3] += h;
                }
            } else {
#pragma unroll
                for (int t = 0; t < 3; ++t)
#pragma unroll
                    for (int j = 0; j < 4; ++j) hq[slot][t][j] = 0.f;
            }

            if (k >= 8) {
                const int r = k - 8;            // output row within segment
#pragma unroll
                for (int j = 0; j < 4; ++j) {
                    // ncc = Sxy / (sqrt(Sxx*Syy) + 25e-8)
                    float rad = fmaxf(oxx[j] * oyy[j], 0.f);  // guard drift
                    float s = sqrtf(rad) + 2.5e-7f;
                    float ncc = oxy[j] * __builtin_amdgcn_rcpf(s);
                    atomicAdd(&acc[r * STRIPW + rs + j], ncc);
                }
            }
        }
    }

    __syncthreads();
    // writeout: mean over 3 channels
    const float inv3 = 1.f / 3.f;
    float* op = outg + (size_t)b * (H * W);
    for (int i = tid; i < HS * STRIPW / 4; i += 192) {
        float4 v = ((const float4*)acc)[i];
        v.x *= inv3; v.y *= inv3; v.z *= inv3; v.w *= inv3;
        int r = i / (STRIPW / 4);
        int c4 = i - r * (STRIPW / 4);
        *(float4*)(op + (size_t)(o0 + r) * W + s0 + c4 * 4) = v;
    }
}

extern "C" void kernel_launch(void* const* d_in, const int* in_sizes, int n_in,
                              void* d_out, int out_size, void* d_ws, size_t ws_size,
                              hipStream_t stream) {
    const float* x = (const float*)d_in[0];
    const float* y = (const float*)d_in[1];
    float* out = (float*)d_out;
    dim3 grid((H / HS) * 2, Bn);  // 128 x 16 = 2048 blocks
    zncc_ring<<<grid, 192, 0, stream>>>(x, y, out);
}